// Round 14
// baseline (138.761 us; speedup 1.0000x reference)
//
#include <hip/hip_runtime.h>
#include <hip/hip_bf16.h>
#include <math.h>

#define B_ 4
#define L_ 1024
#define D_ 256
#define U_ 32
#define KSPLIT 4

// 2*log2(e): q2+k2 pre-scaled so exp2(q2+k2) = e^{2(q+k+bh)}
#define SC2 2.8853900817779268f

#if __has_builtin(__builtin_amdgcn_exp2f)
#define EXP2(x) __builtin_amdgcn_exp2f(x)
#else
#define EXP2(x) exp2f(x)
#endif
#if __has_builtin(__builtin_amdgcn_rcpf)
#define RCP(x) __builtin_amdgcn_rcpf(x)
#else
#define RCP(x) (1.0f / (x))
#endif

typedef __attribute__((ext_vector_type(8))) short bf16x8;  // 8 bf16 (4 VGPRs)
typedef __attribute__((ext_vector_type(4))) float f32x4;
typedef unsigned long long u64;

// manual RNE float->bf16 (self-contained)
__device__ __forceinline__ ushort f2bf(float f) {
  uint b = __float_as_uint(f);
  return (ushort)((b + 0x7fffu + ((b >> 16) & 1u)) >> 16);
}
__device__ __forceinline__ float bf2f(ushort u) {
  return __uint_as_float(((uint)u) << 16);
}
// pack value v as (hi_bf16 << 16) | lo_bf16 with lo = RNE(v - hi)
__device__ __forceinline__ uint packhl(float v) {
  ushort h = f2bf(v);
  ushort l = f2bf(v - bf2f(h));
  return (((uint)h) << 16) | (uint)l;
}
__device__ __forceinline__ u64 hi64(uint4 p) {
  return ((u64)(p.x >> 16)) | ((u64)(p.y >> 16) << 16) |
         ((u64)(p.z >> 16) << 32) | ((u64)(p.w >> 16) << 48);
}
__device__ __forceinline__ u64 lo64(uint4 p) {
  return ((u64)(p.x & 0xffffu)) | ((u64)(p.y & 0xffffu) << 16) |
         ((u64)(p.z & 0xffffu) << 32) | ((u64)(p.w & 0xffffu) << 48);
}
__device__ __forceinline__ uint4 mk128(u64 lo, u64 hi) {
  uint4 r;
  r.x = (uint)lo; r.y = (uint)(lo >> 32);
  r.z = (uint)hi; r.w = (uint)(hi >> 32);
  return r;
}

// -------------------------------------------------------------------------
// K1: 16 rows/block (grid 256). q2 = SC2*(x@Wt + bh), k2 = SC2*(x@Wx);
// xpk[b][d][l] = packed hi|lo bf16 of x^T, written COALESCED along l.
// ba dropped: uniform shift is softmax-invariant.
// -------------------------------------------------------------------------
__global__ __launch_bounds__(256) void k_proj(
    const float* __restrict__ x, const float* __restrict__ Wt,
    const float* __restrict__ Wx, const float* __restrict__ bh,
    float* __restrict__ q2, float* __restrict__ k2, uint* __restrict__ xpk) {
  const int blk = blockIdx.x;            // b*64 + rowblk
  const int b = blk >> 6;
  const int l0 = (blk & 63) * 16;
  const int t = threadIdx.x;
  __shared__ float xr[16][D_];           // 16 KB

  // stage 16 rows of x (coalesced float4)
  const float* xbase = x + ((size_t)(b * L_ + l0)) * D_;
  {
    const int r = t >> 4;
    const int c0 = (t & 15) * 16;
    #pragma unroll
    for (int c = 0; c < 4; ++c)
      *(float4*)&xr[r][c0 + 4 * c] = *(const float4*)&xbase[(size_t)r * D_ + c0 + 4 * c];
  }
  __syncthreads();

  // q/k: thread -> row rr, sel (Wt/Wx), u-quad u0. W float4 stays L1-hot.
  {
    const int rr = t >> 4;
    const int g = t & 15;
    const int sel = g >> 3;
    const int u0 = (g & 7) * 4;
    const float* W = sel ? Wx : Wt;
    float acc0 = 0.f, acc1 = 0.f, acc2 = 0.f, acc3 = 0.f;
    #pragma unroll 8
    for (int d = 0; d < D_; ++d) {
      const float4 w4 = *(const float4*)&W[d * U_ + u0];
      const float xv = xr[rr][d];
      acc0 = fmaf(xv, w4.x, acc0);
      acc1 = fmaf(xv, w4.y, acc1);
      acc2 = fmaf(xv, w4.z, acc2);
      acc3 = fmaf(xv, w4.w, acc3);
    }
    const size_t orow = ((size_t)(b * L_ + l0 + rr)) * U_ + u0;
    if (sel == 0) {
      q2[orow]     = SC2 * (acc0 + bh[u0]);
      q2[orow + 1] = SC2 * (acc1 + bh[u0 + 1]);
      q2[orow + 2] = SC2 * (acc2 + bh[u0 + 2]);
      q2[orow + 3] = SC2 * (acc3 + bh[u0 + 3]);
    } else {
      k2[orow]     = SC2 * acc0;
      k2[orow + 1] = SC2 * acc1;
      k2[orow + 2] = SC2 * acc2;
      k2[orow + 3] = SC2 * acc3;
    }
  }

  // transposed packed write: 4 lanes cover 16 l's of one d-row ->
  // 64B contiguous stores (coalesced).
  {
    const int lq = t & 3;
    #pragma unroll
    for (int s = 0; s < 4; ++s) {
      const int d = 64 * s + (t >> 2);
      uint4 v;
      v.x = packhl(xr[lq * 4 + 0][d]);
      v.y = packhl(xr[lq * 4 + 1][d]);
      v.z = packhl(xr[lq * 4 + 2][d]);
      v.w = packhl(xr[lq * 4 + 3][d]);
      *(uint4*)&xpk[((size_t)(b * D_ + d)) * L_ + l0 + lq * 4] = v;
    }
  }
}

// -------------------------------------------------------------------------
// K2: 256 threads (4 waves), 4 i-rows/block, grid 1024 = 4 blocks/CU.
// TLP fix vs R8: same 2-k-rows-per-lane register footprint (64 VGPR; the
// R10 4-row variant's ~200 VGPR cost 2 waves/SIMD and regressed), but
// half-size blocks so 3-4 waves/SIMD fit -> 12-16 waves/CU vs R8's 8.
// Lane covers j-halves {jh*512+t, jh*512+256+t}, reloading kr between
// halves (k2 is L2-hot, ~2us total). Per element: add, exp2, add, rcp,
// fmac. Softmax via 16KB e-LDS, wave w reduces row w. Output packed bf16.
// -------------------------------------------------------------------------
__global__ __launch_bounds__(256) void k_scores(
    const float* __restrict__ q2, const float* __restrict__ k2,
    const float* __restrict__ Wa, uint* __restrict__ apk) {
  const int blk = blockIdx.x;
  const int b = blk >> 8;                // 256 blocks per batch
  const int i0 = (blk & 255) * 4;
  const int t = threadIdx.x;
  __shared__ float e_lds[4][L_];         // 16 KB

  // block-uniform Wa -> SGPRs
  float wa[32];
  float sumwa = 0.f;
  #pragma unroll
  for (int u = 0; u < 32; ++u) { wa[u] = Wa[u]; sumwa += wa[u]; }

  const float* kb = k2 + (size_t)b * L_ * U_;
  const float* qb = q2 + ((size_t)(b * L_ + i0)) * U_;

  #pragma unroll
  for (int jh = 0; jh < 2; ++jh) {
    // lane's two k rows for this half: j0 = jh*512 + t, j1 = j0 + 256
    float kr0[32], kr1[32];
    #pragma unroll
    for (int c = 0; c < 8; ++c) {
      const float4 v0 = *(const float4*)&kb[(size_t)(jh * 512 + t) * U_ + 4 * c];
      const float4 v1 = *(const float4*)&kb[(size_t)(jh * 512 + 256 + t) * U_ + 4 * c];
      kr0[4 * c] = v0.x; kr0[4 * c + 1] = v0.y; kr0[4 * c + 2] = v0.z; kr0[4 * c + 3] = v0.w;
      kr1[4 * c] = v1.x; kr1[4 * c + 1] = v1.y; kr1[4 * c + 2] = v1.z; kr1[4 * c + 3] = v1.w;
    }

    #pragma unroll
    for (int i = 0; i < 4; ++i) {
      float qv[32];                      // block-uniform -> s_load
      #pragma unroll
      for (int u = 0; u < 32; ++u) qv[u] = qb[i * U_ + u];
      float a00 = 0.f, a01 = 0.f, a10 = 0.f, a11 = 0.f;  // 4 chains
      #pragma unroll
      for (int u = 0; u < 32; u += 2) {
        {
          const float y0 = qv[u] + kr0[u];
          a00 = fmaf(wa[u], RCP(EXP2(y0) + 1.f), a00);
          const float y1 = qv[u] + kr1[u];
          a10 = fmaf(wa[u], RCP(EXP2(y1) + 1.f), a10);
        }
        {
          const float y0 = qv[u + 1] + kr0[u + 1];
          a01 = fmaf(wa[u + 1], RCP(EXP2(y0) + 1.f), a01);
          const float y1 = qv[u + 1] + kr1[u + 1];
          a11 = fmaf(wa[u + 1], RCP(EXP2(y1) + 1.f), a11);
        }
      }
      e_lds[i][jh * 512 + t]       = sumwa - 2.f * (a00 + a01);
      e_lds[i][jh * 512 + 256 + t] = sumwa - 2.f * (a10 + a11);
    }
  }
  __syncthreads();

  // softmax: wave w owns row w (1024 values, 16 per lane, conflict-free)
  const int w = t >> 6;
  const int lane = t & 63;
  float ev[16];
  float m = -1e30f;
  #pragma unroll
  for (int mm = 0; mm < 16; ++mm) {
    ev[mm] = e_lds[w][lane + 64 * mm];
    m = fmaxf(m, ev[mm]);
  }
  #pragma unroll
  for (int off = 32; off >= 1; off >>= 1) m = fmaxf(m, __shfl_xor(m, off, 64));
  float s = 0.f;
  #pragma unroll
  for (int mm = 0; mm < 16; ++mm) { ev[mm] = __expf(ev[mm] - m); s += ev[mm]; }
  #pragma unroll
  for (int off = 32; off >= 1; off >>= 1) s += __shfl_xor(s, off, 64);
  const float rinv = 1.0f / s;
  uint* arow = apk + ((size_t)(b * L_ + i0 + w)) * L_;
  #pragma unroll
  for (int mm = 0; mm < 16; ++mm) arow[lane + 64 * mm] = packhl(ev[mm] * rinv);
}

// -------------------------------------------------------------------------
// K3: v = a @ x via split-bf16 MFMA (ah@xh + al@xh + ah@xl), K-SPLIT x4:
// grid 1024 (4 blocks/CU, 16 waves/CU). Staging via ds_write_b128, octet
// XOR swizzle on write+read (~2-way, free). Partials to psum, reduced by
// K4 (measured best vs atomic epilogue: 134.7 vs 137.3).
// -------------------------------------------------------------------------
#define MFMA16(A, Bf, C) __builtin_amdgcn_mfma_f32_16x16x32_bf16(A, Bf, C, 0, 0, 0)

__global__ __launch_bounds__(256) void k_wsum(
    const uint* __restrict__ apk, const uint* __restrict__ xpk,
    float* __restrict__ psum) {
  const int d0 = blockIdx.x * 64;
  const int i0 = blockIdx.y * 64;
  const int bz = blockIdx.z;
  const int b  = bz & 3;
  const int ks0 = (bz >> 2) * 256;       // K-split offset
  const int t  = threadIdx.x;
  const int lane = t & 63;
  const int w  = t >> 6;
  const int wr = w >> 1;                 // wave row-block (i)
  const int wc = w & 1;                  // wave col-block (d)

  __shared__ f32x4 ldsv[4 * 64 * 8];     // 32 KB: ah,al,xh,xl planes of 8KB
  char* const base = (char*)ldsv;

  // staging map: row = t>>2 (64), kq = t&3 (16 uints each = 16 k-values)
  const int r  = t >> 2;
  const int kq = t & 3;
  const uint* asrc = apk + ((size_t)(b * L_ + i0 + r)) * L_ + ks0 + kq * 16;
  const uint* xsrc = xpk + ((size_t)(b * D_ + d0 + r)) * L_ + ks0 + kq * 16;

  f32x4 acc00 = {0.f, 0.f, 0.f, 0.f}, acc01 = {0.f, 0.f, 0.f, 0.f};
  f32x4 acc10 = {0.f, 0.f, 0.f, 0.f}, acc11 = {0.f, 0.f, 0.f, 0.f};

  uint4 ra[4], rx[4];
  #pragma unroll
  for (int c = 0; c < 4; ++c) {
    ra[c] = *(const uint4*)(asrc + 4 * c);
    rx[c] = *(const uint4*)(xsrc + 4 * c);
  }

  for (int step = 0; step < 4; ++step) { // 4 x BK=64 over this K chunk
    __syncthreads();
    // stage: per thread 2x b128 hi + 2x b128 lo per operand
    #pragma unroll
    for (int h = 0; h < 2; ++h) {        // h: which 8-k slot pair half
      const int ub = (kq * 2 + h) ^ (r & 7);
      const int off = r * 128 + (ub << 4);
      *(uint4*)(base + off)         = mk128(hi64(ra[2 * h]), hi64(ra[2 * h + 1]));
      *(uint4*)(base + off + 8192)  = mk128(lo64(ra[2 * h]), lo64(ra[2 * h + 1]));
      *(uint4*)(base + off + 16384) = mk128(hi64(rx[2 * h]), hi64(rx[2 * h + 1]));
      *(uint4*)(base + off + 24576) = mk128(lo64(rx[2 * h]), lo64(rx[2 * h + 1]));
    }
    if (step < 3) {                      // prefetch next K-tile
      #pragma unroll
      for (int c = 0; c < 4; ++c) {
        ra[c] = *(const uint4*)(asrc + (step + 1) * 64 + 4 * c);
        rx[c] = *(const uint4*)(xsrc + (step + 1) * 64 + 4 * c);
      }
    }
    __syncthreads();

    #pragma unroll
    for (int ks = 0; ks < 2; ++ks) {
      const int ub = ks * 4 + (lane >> 4);
      auto frag = [&](int plane, int rbase) -> bf16x8 {
        const int rr = rbase + (lane & 15);
        const int off = plane * 8192 + rr * 128 + (((ub ^ (rr & 7))) << 4);
        return *(const bf16x8*)(base + off);
      };
      const bf16x8 ah0 = frag(0, wr * 32), ah1 = frag(0, wr * 32 + 16);
      const bf16x8 al0 = frag(1, wr * 32), al1 = frag(1, wr * 32 + 16);
      const bf16x8 xh0 = frag(2, wc * 32), xh1 = frag(2, wc * 32 + 16);
      const bf16x8 xl0 = frag(3, wc * 32), xl1 = frag(3, wc * 32 + 16);
      acc00 = MFMA16(ah0, xh0, acc00); acc00 = MFMA16(al0, xh0, acc00); acc00 = MFMA16(ah0, xl0, acc00);
      acc01 = MFMA16(ah0, xh1, acc01); acc01 = MFMA16(al0, xh1, acc01); acc01 = MFMA16(ah0, xl1, acc01);
      acc10 = MFMA16(ah1, xh0, acc10); acc10 = MFMA16(al1, xh0, acc10); acc10 = MFMA16(ah1, xl0, acc10);
      acc11 = MFMA16(ah1, xh1, acc11); acc11 = MFMA16(al1, xh1, acc11); acc11 = MFMA16(ah1, xl1, acc11);
    }
  }

  // C/D layout: col = lane&15, row = (lane>>4)*4 + reg. psum plane = bz.
  const int crow = (lane >> 4) * 4;
  const int ccol = lane & 15;
  float* pb = psum + (size_t)bz * L_ * D_;
  #pragma unroll
  for (int m2 = 0; m2 < 2; ++m2) {
    #pragma unroll
    for (int n2 = 0; n2 < 2; ++n2) {
      const f32x4 acc = m2 == 0 ? (n2 == 0 ? acc00 : acc01)
                                : (n2 == 0 ? acc10 : acc11);
      const int col = d0 + wc * 32 + n2 * 16 + ccol;
      #pragma unroll
      for (int jj = 0; jj < 4; ++jj) {
        const int rowi = i0 + wr * 32 + m2 * 16 + crow + jj;
        pb[(size_t)rowi * D_ + col] = acc[jj];
      }
    }
  }
}

// -------------------------------------------------------------------------
// K4: out[e] = sum_s psum[s*n + e], n = B*L*D (4 K-split plane sets).
// -------------------------------------------------------------------------
__global__ __launch_bounds__(256) void k_reduce(
    const float4* __restrict__ p, float4* __restrict__ o) {
  const size_t n = (size_t)B_ * L_ * D_ / 4;  // 1M float4 per split-plane set
  size_t i = (size_t)blockIdx.x * 256 + threadIdx.x;
  const size_t stride = (size_t)gridDim.x * 256;
  for (; i < n; i += stride) {
    const float4 a = p[i];
    const float4 b2 = p[i + n];
    const float4 c = p[i + 2 * n];
    const float4 d = p[i + 3 * n];
    float4 r;
    r.x = (a.x + b2.x) + (c.x + d.x);
    r.y = (a.y + b2.y) + (c.y + d.y);
    r.z = (a.z + b2.z) + (c.z + d.z);
    r.w = (a.w + b2.w) + (c.w + d.w);
    o[i] = r;
  }
}

// -------------------------------------------------------------------------
extern "C" void kernel_launch(void* const* d_in, const int* in_sizes, int n_in,
                              void* d_out, int out_size, void* d_ws, size_t ws_size,
                              hipStream_t stream) {
  const float* x  = (const float*)d_in[0];
  const float* Wt = (const float*)d_in[1];
  const float* Wx = (const float*)d_in[2];
  const float* bh = (const float*)d_in[3];
  const float* Wa = (const float*)d_in[4];
  // d_in[5] = ba: uniform shift of all scores -> softmax-invariant -> dropped.
  float* out = (float*)d_out;
  float* ws = (float*)d_ws;
  float* q2 = ws;                                      // 0.5 MB
  float* k2 = ws + (size_t)B_ * L_ * U_;               // 0.5 MB
  uint* apk = (uint*)(ws + (size_t)2 * B_ * L_ * U_);  // 16 MB
  uint* xpk = apk + (size_t)B_ * L_ * L_;              // 4 MB
  float* psum = (float*)(xpk + (size_t)B_ * D_ * L_);  // 16 MB (4 split planes)
  if (ws_size < (size_t)38797312) return;              // 37 MB guard

  k_proj<<<B_ * L_ / 16, 256, 0, stream>>>(x, Wt, Wx, bh, q2, k2, xpk);
  k_scores<<<B_ * (L_ / 4), 256, 0, stream>>>(q2, k2, Wa, apk);
  dim3 g3(D_ / 64, L_ / 64, B_ * KSPLIT);
  k_wsum<<<g3, 256, 0, stream>>>(apk, xpk, psum);
  k_reduce<<<1024, 256, 0, stream>>>((const float4*)psum, (float4*)out);
}

// Round 15
// 133.359 us; speedup vs baseline: 1.0405x; 1.0405x over previous
//
#include <hip/hip_runtime.h>
#include <hip/hip_bf16.h>
#include <math.h>

#define B_ 4
#define L_ 1024
#define D_ 256
#define U_ 32
#define KSPLIT 4

// 2*log2(e): q2+k2 pre-scaled so exp2(q2+k2) = e^{2(q+k+bh)}
#define SC2 2.8853900817779268f

#if __has_builtin(__builtin_amdgcn_exp2f)
#define EXP2(x) __builtin_amdgcn_exp2f(x)
#else
#define EXP2(x) exp2f(x)
#endif
#if __has_builtin(__builtin_amdgcn_rcpf)
#define RCP(x) __builtin_amdgcn_rcpf(x)
#else
#define RCP(x) (1.0f / (x))
#endif

typedef __attribute__((ext_vector_type(8))) short bf16x8;  // 8 bf16 (4 VGPRs)
typedef __attribute__((ext_vector_type(4))) float f32x4;
typedef unsigned long long u64;

// manual RNE float->bf16 (self-contained)
__device__ __forceinline__ ushort f2bf(float f) {
  uint b = __float_as_uint(f);
  return (ushort)((b + 0x7fffu + ((b >> 16) & 1u)) >> 16);
}
__device__ __forceinline__ float bf2f(ushort u) {
  return __uint_as_float(((uint)u) << 16);
}
// pack value v as (hi_bf16 << 16) | lo_bf16 with lo = RNE(v - hi)
__device__ __forceinline__ uint packhl(float v) {
  ushort h = f2bf(v);
  ushort l = f2bf(v - bf2f(h));
  return (((uint)h) << 16) | (uint)l;
}
__device__ __forceinline__ u64 hi64(uint4 p) {
  return ((u64)(p.x >> 16)) | ((u64)(p.y >> 16) << 16) |
         ((u64)(p.z >> 16) << 32) | ((u64)(p.w >> 16) << 48);
}
__device__ __forceinline__ u64 lo64(uint4 p) {
  return ((u64)(p.x & 0xffffu)) | ((u64)(p.y & 0xffffu) << 16) |
         ((u64)(p.z & 0xffffu) << 32) | ((u64)(p.w & 0xffffu) << 48);
}
__device__ __forceinline__ uint4 mk128(u64 lo, u64 hi) {
  uint4 r;
  r.x = (uint)lo; r.y = (uint)(lo >> 32);
  r.z = (uint)hi; r.w = (uint)(hi >> 32);
  return r;
}

// -------------------------------------------------------------------------
// K1: 16 rows/block (grid 256). q2 = SC2*(x@Wt + bh), k2 = SC2*(x@Wx);
// xpk[b][d][l] = packed hi|lo bf16 of x^T, written COALESCED along l.
// ba dropped: uniform shift is softmax-invariant.
// -------------------------------------------------------------------------
__global__ __launch_bounds__(256) void k_proj(
    const float* __restrict__ x, const float* __restrict__ Wt,
    const float* __restrict__ Wx, const float* __restrict__ bh,
    float* __restrict__ q2, float* __restrict__ k2, uint* __restrict__ xpk) {
  const int blk = blockIdx.x;            // b*64 + rowblk
  const int b = blk >> 6;
  const int l0 = (blk & 63) * 16;
  const int t = threadIdx.x;
  __shared__ float xr[16][D_];           // 16 KB

  // stage 16 rows of x (coalesced float4)
  const float* xbase = x + ((size_t)(b * L_ + l0)) * D_;
  {
    const int r = t >> 4;
    const int c0 = (t & 15) * 16;
    #pragma unroll
    for (int c = 0; c < 4; ++c)
      *(float4*)&xr[r][c0 + 4 * c] = *(const float4*)&xbase[(size_t)r * D_ + c0 + 4 * c];
  }
  __syncthreads();

  // q/k: thread -> row rr, sel (Wt/Wx), u-quad u0. W float4 stays L1-hot.
  {
    const int rr = t >> 4;
    const int g = t & 15;
    const int sel = g >> 3;
    const int u0 = (g & 7) * 4;
    const float* W = sel ? Wx : Wt;
    float acc0 = 0.f, acc1 = 0.f, acc2 = 0.f, acc3 = 0.f;
    #pragma unroll 8
    for (int d = 0; d < D_; ++d) {
      const float4 w4 = *(const float4*)&W[d * U_ + u0];
      const float xv = xr[rr][d];
      acc0 = fmaf(xv, w4.x, acc0);
      acc1 = fmaf(xv, w4.y, acc1);
      acc2 = fmaf(xv, w4.z, acc2);
      acc3 = fmaf(xv, w4.w, acc3);
    }
    const size_t orow = ((size_t)(b * L_ + l0 + rr)) * U_ + u0;
    if (sel == 0) {
      q2[orow]     = SC2 * (acc0 + bh[u0]);
      q2[orow + 1] = SC2 * (acc1 + bh[u0 + 1]);
      q2[orow + 2] = SC2 * (acc2 + bh[u0 + 2]);
      q2[orow + 3] = SC2 * (acc3 + bh[u0 + 3]);
    } else {
      k2[orow]     = SC2 * acc0;
      k2[orow + 1] = SC2 * acc1;
      k2[orow + 2] = SC2 * acc2;
      k2[orow + 3] = SC2 * acc3;
    }
  }

  // transposed packed write: 4 lanes cover 16 l's of one d-row ->
  // 64B contiguous stores (coalesced).
  {
    const int lq = t & 3;
    #pragma unroll
    for (int s = 0; s < 4; ++s) {
      const int d = 64 * s + (t >> 2);
      uint4 v;
      v.x = packhl(xr[lq * 4 + 0][d]);
      v.y = packhl(xr[lq * 4 + 1][d]);
      v.z = packhl(xr[lq * 4 + 2][d]);
      v.w = packhl(xr[lq * 4 + 3][d]);
      *(uint4*)&xpk[((size_t)(b * D_ + d)) * L_ + l0 + lq * 4] = v;
    }
  }
}

// -------------------------------------------------------------------------
// K2: 512 threads, 8 rows per block; each lane owns k-rows {t, t+512} in
// 64 VGPRs (VGPR ~148 keeps them RESIDENT — the 256-thr reshape dropped
// to VGPR 40 with per-use L2 reloads and ran 43us vs this shape's ~25;
// measured R14 vs R8). q rows + Wa block-uniform -> scalarized. Per
// element: add, exp2, add, rcp, fmac — issue-slot floor ~19us.
// Softmax via 32KB e-LDS, wave w reduces row w. Output packed hi|lo bf16.
// -------------------------------------------------------------------------
__global__ __launch_bounds__(512) void k_scores(
    const float* __restrict__ q2, const float* __restrict__ k2,
    const float* __restrict__ Wa, uint* __restrict__ apk) {
  const int blk = blockIdx.x;
  const int b = blk >> 7;                // / (L_/8)
  const int i0 = (blk & 127) * 8;
  const int t = threadIdx.x;
  __shared__ float e_lds[8][L_];

  const float* kb = k2 + (size_t)b * L_ * U_;
  float kr0[32], kr1[32];
  #pragma unroll
  for (int c = 0; c < 8; ++c) {
    const float4 v0 = *(const float4*)&kb[(size_t)t * U_ + 4 * c];
    const float4 v1 = *(const float4*)&kb[(size_t)(t + 512) * U_ + 4 * c];
    kr0[4 * c] = v0.x; kr0[4 * c + 1] = v0.y; kr0[4 * c + 2] = v0.z; kr0[4 * c + 3] = v0.w;
    kr1[4 * c] = v1.x; kr1[4 * c + 1] = v1.y; kr1[4 * c + 2] = v1.z; kr1[4 * c + 3] = v1.w;
  }

  float wa[32];
  float sumwa = 0.f;
  #pragma unroll
  for (int u = 0; u < 32; ++u) { wa[u] = Wa[u]; sumwa += wa[u]; }

  const float* qb = q2 + ((size_t)(b * L_ + i0)) * U_;
  #pragma unroll
  for (int i = 0; i < 8; ++i) {
    float qv[32];
    #pragma unroll
    for (int u = 0; u < 32; ++u) qv[u] = qb[i * U_ + u];
    float a00 = 0.f, a01 = 0.f, a10 = 0.f, a11 = 0.f;
    #pragma unroll
    for (int u = 0; u < 32; u += 2) {
      {
        const float y0 = qv[u] + kr0[u];
        const float r0 = RCP(EXP2(y0) + 1.f);
        a00 = fmaf(wa[u], r0, a00);
        const float y1 = qv[u] + kr1[u];
        const float r1 = RCP(EXP2(y1) + 1.f);
        a10 = fmaf(wa[u], r1, a10);
      }
      {
        const float y0 = qv[u + 1] + kr0[u + 1];
        const float r0 = RCP(EXP2(y0) + 1.f);
        a01 = fmaf(wa[u + 1], r0, a01);
        const float y1 = qv[u + 1] + kr1[u + 1];
        const float r1 = RCP(EXP2(y1) + 1.f);
        a11 = fmaf(wa[u + 1], r1, a11);
      }
    }
    e_lds[i][t]       = sumwa - 2.f * (a00 + a01);
    e_lds[i][t + 512] = sumwa - 2.f * (a10 + a11);
  }
  __syncthreads();

  const int w = t >> 6;
  const int lane = t & 63;
  float ev[16];
  float m = -1e30f;
  #pragma unroll
  for (int mm = 0; mm < 16; ++mm) {
    ev[mm] = e_lds[w][lane + 64 * mm];
    m = fmaxf(m, ev[mm]);
  }
  #pragma unroll
  for (int off = 32; off >= 1; off >>= 1) m = fmaxf(m, __shfl_xor(m, off, 64));
  float s = 0.f;
  #pragma unroll
  for (int mm = 0; mm < 16; ++mm) { ev[mm] = __expf(ev[mm] - m); s += ev[mm]; }
  #pragma unroll
  for (int off = 32; off >= 1; off >>= 1) s += __shfl_xor(s, off, 64);
  const float rinv = 1.0f / s;
  uint* arow = apk + ((size_t)(b * L_ + i0 + w)) * L_;
  #pragma unroll
  for (int mm = 0; mm < 16; ++mm) arow[lane + 64 * mm] = packhl(ev[mm] * rinv);
}

// -------------------------------------------------------------------------
// K3: v = a @ x via split-bf16 MFMA (ah@xh + al@xh + ah@xl), K-SPLIT x4:
// grid 1024 (4 blocks/CU, 16 waves/CU). Staging via ds_write_b128, octet
// XOR swizzle on write+read (~2-way, free). Partials to psum, reduced by
// K4 (measured best vs atomic epilogue: 134.7 vs 137.3).
// -------------------------------------------------------------------------
#define MFMA16(A, Bf, C) __builtin_amdgcn_mfma_f32_16x16x32_bf16(A, Bf, C, 0, 0, 0)

__global__ __launch_bounds__(256) void k_wsum(
    const uint* __restrict__ apk, const uint* __restrict__ xpk,
    float* __restrict__ psum) {
  const int d0 = blockIdx.x * 64;
  const int i0 = blockIdx.y * 64;
  const int bz = blockIdx.z;
  const int b  = bz & 3;
  const int ks0 = (bz >> 2) * 256;       // K-split offset
  const int t  = threadIdx.x;
  const int lane = t & 63;
  const int w  = t >> 6;
  const int wr = w >> 1;                 // wave row-block (i)
  const int wc = w & 1;                  // wave col-block (d)

  __shared__ f32x4 ldsv[4 * 64 * 8];     // 32 KB: ah,al,xh,xl planes of 8KB
  char* const base = (char*)ldsv;

  // staging map: row = t>>2 (64), kq = t&3 (16 uints each = 16 k-values)
  const int r  = t >> 2;
  const int kq = t & 3;
  const uint* asrc = apk + ((size_t)(b * L_ + i0 + r)) * L_ + ks0 + kq * 16;
  const uint* xsrc = xpk + ((size_t)(b * D_ + d0 + r)) * L_ + ks0 + kq * 16;

  f32x4 acc00 = {0.f, 0.f, 0.f, 0.f}, acc01 = {0.f, 0.f, 0.f, 0.f};
  f32x4 acc10 = {0.f, 0.f, 0.f, 0.f}, acc11 = {0.f, 0.f, 0.f, 0.f};

  uint4 ra[4], rx[4];
  #pragma unroll
  for (int c = 0; c < 4; ++c) {
    ra[c] = *(const uint4*)(asrc + 4 * c);
    rx[c] = *(const uint4*)(xsrc + 4 * c);
  }

  for (int step = 0; step < 4; ++step) { // 4 x BK=64 over this K chunk
    __syncthreads();
    // stage: per thread 2x b128 hi + 2x b128 lo per operand
    #pragma unroll
    for (int h = 0; h < 2; ++h) {        // h: which 8-k slot pair half
      const int ub = (kq * 2 + h) ^ (r & 7);
      const int off = r * 128 + (ub << 4);
      *(uint4*)(base + off)         = mk128(hi64(ra[2 * h]), hi64(ra[2 * h + 1]));
      *(uint4*)(base + off + 8192)  = mk128(lo64(ra[2 * h]), lo64(ra[2 * h + 1]));
      *(uint4*)(base + off + 16384) = mk128(hi64(rx[2 * h]), hi64(rx[2 * h + 1]));
      *(uint4*)(base + off + 24576) = mk128(lo64(rx[2 * h]), lo64(rx[2 * h + 1]));
    }
    if (step < 3) {                      // prefetch next K-tile
      #pragma unroll
      for (int c = 0; c < 4; ++c) {
        ra[c] = *(const uint4*)(asrc + (step + 1) * 64 + 4 * c);
        rx[c] = *(const uint4*)(xsrc + (step + 1) * 64 + 4 * c);
      }
    }
    __syncthreads();

    #pragma unroll
    for (int ks = 0; ks < 2; ++ks) {
      const int ub = ks * 4 + (lane >> 4);
      auto frag = [&](int plane, int rbase) -> bf16x8 {
        const int rr = rbase + (lane & 15);
        const int off = plane * 8192 + rr * 128 + (((ub ^ (rr & 7))) << 4);
        return *(const bf16x8*)(base + off);
      };
      const bf16x8 ah0 = frag(0, wr * 32), ah1 = frag(0, wr * 32 + 16);
      const bf16x8 al0 = frag(1, wr * 32), al1 = frag(1, wr * 32 + 16);
      const bf16x8 xh0 = frag(2, wc * 32), xh1 = frag(2, wc * 32 + 16);
      const bf16x8 xl0 = frag(3, wc * 32), xl1 = frag(3, wc * 32 + 16);
      acc00 = MFMA16(ah0, xh0, acc00); acc00 = MFMA16(al0, xh0, acc00); acc00 = MFMA16(ah0, xl0, acc00);
      acc01 = MFMA16(ah0, xh1, acc01); acc01 = MFMA16(al0, xh1, acc01); acc01 = MFMA16(ah0, xl1, acc01);
      acc10 = MFMA16(ah1, xh0, acc10); acc10 = MFMA16(al1, xh0, acc10); acc10 = MFMA16(ah1, xl0, acc10);
      acc11 = MFMA16(ah1, xh1, acc11); acc11 = MFMA16(al1, xh1, acc11); acc11 = MFMA16(ah1, xl1, acc11);
    }
  }

  // C/D layout: col = lane&15, row = (lane>>4)*4 + reg. psum plane = bz.
  const int crow = (lane >> 4) * 4;
  const int ccol = lane & 15;
  float* pb = psum + (size_t)bz * L_ * D_;
  #pragma unroll
  for (int m2 = 0; m2 < 2; ++m2) {
    #pragma unroll
    for (int n2 = 0; n2 < 2; ++n2) {
      const f32x4 acc = m2 == 0 ? (n2 == 0 ? acc00 : acc01)
                                : (n2 == 0 ? acc10 : acc11);
      const int col = d0 + wc * 32 + n2 * 16 + ccol;
      #pragma unroll
      for (int jj = 0; jj < 4; ++jj) {
        const int rowi = i0 + wr * 32 + m2 * 16 + crow + jj;
        pb[(size_t)rowi * D_ + col] = acc[jj];
      }
    }
  }
}

// -------------------------------------------------------------------------
// K4: out[e] = sum_s psum[s*n + e], n = B*L*D (4 K-split plane sets).
// -------------------------------------------------------------------------
__global__ __launch_bounds__(256) void k_reduce(
    const float4* __restrict__ p, float4* __restrict__ o) {
  const size_t n = (size_t)B_ * L_ * D_ / 4;  // 1M float4 per split-plane set
  size_t i = (size_t)blockIdx.x * 256 + threadIdx.x;
  const size_t stride = (size_t)gridDim.x * 256;
  for (; i < n; i += stride) {
    const float4 a = p[i];
    const float4 b2 = p[i + n];
    const float4 c = p[i + 2 * n];
    const float4 d = p[i + 3 * n];
    float4 r;
    r.x = (a.x + b2.x) + (c.x + d.x);
    r.y = (a.y + b2.y) + (c.y + d.y);
    r.z = (a.z + b2.z) + (c.z + d.z);
    r.w = (a.w + b2.w) + (c.w + d.w);
    o[i] = r;
  }
}

// -------------------------------------------------------------------------
extern "C" void kernel_launch(void* const* d_in, const int* in_sizes, int n_in,
                              void* d_out, int out_size, void* d_ws, size_t ws_size,
                              hipStream_t stream) {
  const float* x  = (const float*)d_in[0];
  const float* Wt = (const float*)d_in[1];
  const float* Wx = (const float*)d_in[2];
  const float* bh = (const float*)d_in[3];
  const float* Wa = (const float*)d_in[4];
  // d_in[5] = ba: uniform shift of all scores -> softmax-invariant -> dropped.
  float* out = (float*)d_out;
  float* ws = (float*)d_ws;
  float* q2 = ws;                                      // 0.5 MB
  float* k2 = ws + (size_t)B_ * L_ * U_;               // 0.5 MB
  uint* apk = (uint*)(ws + (size_t)2 * B_ * L_ * U_);  // 16 MB
  uint* xpk = apk + (size_t)B_ * L_ * L_;              // 4 MB
  float* psum = (float*)(xpk + (size_t)B_ * D_ * L_);  // 16 MB (4 split planes)
  if (ws_size < (size_t)38797312) return;              // 37 MB guard

  k_proj<<<B_ * L_ / 16, 256, 0, stream>>>(x, Wt, Wx, bh, q2, k2, xpk);
  k_scores<<<B_ * (L_ / 8), 512, 0, stream>>>(q2, k2, Wa, apk);
  dim3 g3(D_ / 64, L_ / 64, B_ * KSPLIT);
  k_wsum<<<g3, 256, 0, stream>>>(apk, xpk, psum);
  k_reduce<<<1024, 256, 0, stream>>>((const float4*)psum, (float4*)out);
}